// Round 2
// baseline (460.858 us; speedup 1.0000x reference)
//
#include <hip/hip_runtime.h>
#include <hip/hip_bf16.h>
#include <math.h>

typedef __attribute__((ext_vector_type(4))) float f32x4;
typedef __attribute__((ext_vector_type(8))) short short8;
typedef unsigned short ushort_t;
typedef unsigned int uint_t;

__device__ __forceinline__ float b2f(unsigned short u) {
    unsigned int v = ((unsigned int)u) << 16;
    return __uint_as_float(v);
}
__device__ __forceinline__ unsigned short f2b(float f) {
    unsigned int x = __float_as_uint(f);
    unsigned int r = (x + 0x7fffu + ((x >> 16) & 1u)) >> 16;
    return (unsigned short)r;
}

// ---------------------------------------------------------------- small prep
__global__ void zero_kernel(int* p, int n) {
    int i = blockIdx.x * 256 + threadIdx.x;
    if (i < n) p[i] = 0;
}

// WbT[n][k] (bf16, [256,128]) = B^T of [W1|W2] so PQ = h @ [W1|W2]
__global__ void pack_wb(const float* __restrict__ W_pre, ushort_t* __restrict__ WbT) {
    int i = blockIdx.x * 256 + threadIdx.x;
    if (i >= 256 * 128) return;
    int nn = i >> 7, k = i & 127;
    float v = (nn < 128) ? W_pre[k * 128 + nn] : W_pre[(128 + k) * 128 + (nn - 128)];
    WbT[i] = f2b(v);
}

// WcT[n][k] (bf16, [384,896]): block matrix [[Wp0,0,0],[Wp1,Wp2,Wp3]] transposed
__global__ void pack_wc(const float* __restrict__ W_post, ushort_t* __restrict__ WcT) {
    int i = blockIdx.x * 256 + threadIdx.x;
    if (i >= 384 * 896) return;
    int nn = i / 896, k = i % 896;
    float v;
    if (k < 128) {
        v = (nn < 128) ? W_post[k * 128 + nn] : 0.f;
    } else {
        int ka = k - 128;
        if (nn < 128)      v = W_post[(128 + ka) * 128 + nn];
        else if (nn < 256) v = W_post[(896 + ka) * 128 + (nn - 128)];
        else               v = W_post[(1664 + ka) * 128 + (nn - 256)];
    }
    WcT[i] = f2b(v);
}

// X[:,0:128] = bf16(h)   (X row stride 896)
__global__ void conv_h(const float* __restrict__ h, ushort_t* __restrict__ X, int Nn) {
    int g = blockIdx.x * 256 + threadIdx.x;
    if (g >= Nn * 32) return;
    int n = g >> 5, c4 = (g & 31) * 4;
    float4 hv = *(const float4*)&h[(size_t)n * 128 + c4];
    ushort4 o;
    o.x = f2b(hv.x); o.y = f2b(hv.y); o.z = f2b(hv.z); o.w = f2b(hv.w);
    *(ushort4*)&X[(size_t)n * 896 + c4] = o;
}

// ---------------------------------------------------------------- CSR build
__global__ void hist_kernel(const int* __restrict__ dst, int* __restrict__ counts, int E) {
    int i = blockIdx.x * 256 + threadIdx.x;
    if (i < E) atomicAdd(&counts[dst[i]], 1);
}

// single block exclusive scan over counts[0..Nn-1] -> offsets (in place) + cursors
__global__ __launch_bounds__(1024) void scan_kernel(int* __restrict__ counts,
                                                    int* __restrict__ cursors, int Nn) {
    __shared__ int part[1024];
    int t = threadIdx.x;
    int base = t * 40;
    int loc[40];
    int s = 0;
#pragma unroll
    for (int i = 0; i < 40; ++i) {
        int idx = base + i;
        int v = (idx < Nn) ? counts[idx] : 0;
        loc[i] = s; s += v;
    }
    part[t] = s;
    __syncthreads();
    for (int off = 1; off < 1024; off <<= 1) {
        int v = part[t];
        int u = (t >= off) ? part[t - off] : 0;
        __syncthreads();
        part[t] = v + u;
        __syncthreads();
    }
    int pre = (t > 0) ? part[t - 1] : 0;
#pragma unroll
    for (int i = 0; i < 40; ++i) {
        int idx = base + i;
        if (idx < Nn) { int o = pre + loc[i]; counts[idx] = o; cursors[idx] = o; }
    }
    if (t == 1023) counts[Nn] = part[1023];
}

// scatter + pre-gather into CSR slot order: se, eig_src, efp streams
__global__ void scatter_kernel(const int* __restrict__ dst, const int* __restrict__ src,
                               const float* __restrict__ eig, const float* __restrict__ ef,
                               int* __restrict__ cursors,
                               int* __restrict__ se, float* __restrict__ eig_src,
                               float* __restrict__ efp, int E) {
    int i = blockIdx.x * 256 + threadIdx.x;
    if (i < E) {
        int v = dst[i];
        int p = atomicAdd(&cursors[v], 1);
        int s = src[i];
        se[p] = s;
        eig_src[p] = eig[s * 2 + 1];
        const float4* e4 = (const float4*)(ef + (size_t)i * 16);
        float4 a = e4[0], b = e4[1], c = e4[2], d = e4[3];
        float4* o4 = (float4*)(efp + (size_t)p * 16);
        o4[0] = a; o4[1] = b; o4[2] = c; o4[3] = d;
    }
}

// ---------------------------------------------------------------- bf16 MFMA GEMM (B^T)
// C[M,N] = A[M,K](bf16,lda) @ Bt[N,K]^T(bf16,ldb=K).  128x128 tile, BK=64, 4 waves.
// 1-D grid; bijective XCD remap, n-tile fastest => A-panel shared within an XCD's L2.
template <int OUT_BF16>
__global__ __launch_bounds__(256) void gemm_bt(const ushort_t* __restrict__ A, int lda,
                                               const ushort_t* __restrict__ Bt, int ldb,
                                               void* __restrict__ Cv, int ldc,
                                               int M, int K, int NT) {
    __shared__ ushort_t ldsbuf[2 * 128 * 64];
    const int tid = threadIdx.x, wid = tid >> 6, lane = tid & 63;
    int nwg = gridDim.x;
    int orig = blockIdx.x;
    int q8 = nwg >> 3, r8 = nwg & 7;
    int xcd = orig & 7, local = orig >> 3;
    int wg = (xcd < r8 ? xcd * (q8 + 1) : r8 * (q8 + 1) + (xcd - r8) * q8) + local;
    const int m0 = (wg / NT) * 128, n0 = (wg % NT) * 128;
    f32x4 acc[4][4] = {};
    const int wrow = (wid >> 1) * 64, wcol = (wid & 1) * 64;

    for (int kt = 0; kt < K; kt += 64) {
#pragma unroll
        for (int rnd = 0; rnd < 4; ++rnd) {
            int libase = rnd * 256 + wid * 64;
            {   // A tile: chunk li = r*8 + (c ^ (r&7)), 16B chunks
                int lc = libase + lane;
                int r = lc >> 3, cs = lc & 7;
                int c = cs ^ (r & 7);
                int row = m0 + r; row = row < M ? row : M - 1;
                const ushort_t* g = A + (size_t)row * lda + (kt + c * 8);
                __builtin_amdgcn_global_load_lds(
                    (const __attribute__((address_space(1))) unsigned int*)g,
                    (__attribute__((address_space(3))) unsigned int*)&ldsbuf[(size_t)libase * 8],
                    16, 0, 0);
            }
            {   // B tile (rows of Bt)
                int lc = libase + lane;
                int r = lc >> 3, cs = lc & 7;
                int c = cs ^ (r & 7);
                const ushort_t* g = Bt + (size_t)(n0 + r) * ldb + (kt + c * 8);
                __builtin_amdgcn_global_load_lds(
                    (const __attribute__((address_space(1))) unsigned int*)g,
                    (__attribute__((address_space(3))) unsigned int*)&ldsbuf[8192 + (size_t)libase * 8],
                    16, 0, 0);
            }
        }
        __syncthreads();
#pragma unroll
        for (int kk = 0; kk < 2; ++kk) {
            short8 af[4], bfr[4];
#pragma unroll
            for (int f = 0; f < 4; ++f) {
                int r = wrow + f * 16 + (lane & 15);
                int c16 = kk * 4 + (lane >> 4);
                int ch = r * 8 + (c16 ^ (r & 7));
                af[f] = *(const short8*)&ldsbuf[ch * 8];
            }
#pragma unroll
            for (int f = 0; f < 4; ++f) {
                int r = wcol + f * 16 + (lane & 15);
                int c16 = kk * 4 + (lane >> 4);
                int ch = r * 8 + (c16 ^ (r & 7));
                bfr[f] = *(const short8*)&ldsbuf[8192 + ch * 8];
            }
#pragma unroll
            for (int i = 0; i < 4; ++i)
#pragma unroll
                for (int j = 0; j < 4; ++j)
                    acc[i][j] = __builtin_amdgcn_mfma_f32_16x16x32_bf16(af[i], bfr[j], acc[i][j], 0, 0, 0);
        }
        __syncthreads();
    }
#pragma unroll
    for (int i = 0; i < 4; ++i)
#pragma unroll
        for (int j = 0; j < 4; ++j)
#pragma unroll
            for (int q = 0; q < 4; ++q) {
                int row = m0 + wrow + i * 16 + (lane >> 4) * 4 + q;
                int col = n0 + wcol + j * 16 + (lane & 15);
                if (row < M) {
                    if (OUT_BF16) ((ushort_t*)Cv)[(size_t)row * ldc + col] = f2b(acc[i][j][q]);
                    else          ((float*)Cv)[(size_t)row * ldc + col] = acc[i][j][q];
                }
            }
}

// ---------------------------------------------------------------- aggregation
// one wave per node; all per-edge inputs are CSR-order streams except the PQ gather.
__global__ __launch_bounds__(256) void agg_kernel(
    const ushort_t* __restrict__ PQ, ushort_t* __restrict__ X,
    const float* __restrict__ efp, const float* __restrict__ eig_src,
    const int* __restrict__ se, const int* __restrict__ offs,
    const float* __restrict__ eig, const float* __restrict__ h,
    const float* __restrict__ W_pre, const float* __restrict__ b_pre,
    float* __restrict__ scal, int Nn) {
    __shared__ float W3s[16][128];
    __shared__ float bps[128];
    int tid = threadIdx.x;
    for (int i = tid; i < 2048; i += 256) {
        int j = i >> 7, c = i & 127;
        W3s[j][c] = W_pre[(256 + j) * 128 + c];
    }
    if (tid < 128) bps[tid] = b_pre[tid];
    __syncthreads();
    int wid = tid >> 6, lane = tid & 63;
    int n = blockIdx.x * 4 + wid;
    if (n >= Nn) return;
    int off0 = offs[n], off1 = offs[n + 1];
    int deg = off1 - off0;
    int d0 = lane * 2;

    uint_t qw = *(const uint_t*)&PQ[(size_t)n * 256 + 128 + d0];
    float qb0 = b2f((ushort_t)(qw & 0xffff)) + bps[d0];
    float qb1 = b2f((ushort_t)(qw >> 16)) + bps[d0 + 1];
    float eigd = eig[n * 2 + 1];

    float s0 = 0, s1 = 0, ss0 = 0, ss1 = 0, av0 = 0, av1 = 0, dv0 = 0, dv1 = 0, den = 0;
    float mx0 = -1e30f, mx1 = -1e30f, mn0 = 1e30f, mn1 = 1e30f;

#define EDGE_BODY(IDX, ES, PW)                                                      \
    {                                                                               \
        const float4* ep = (const float4*)(efp + (size_t)(IDX) * 16);               \
        float4 ea = ep[0], eb = ep[1], ec = ep[2], ed = ep[3];                      \
        float ev[16] = {ea.x, ea.y, ea.z, ea.w, eb.x, eb.y, eb.z, eb.w,             \
                        ec.x, ec.y, ec.z, ec.w, ed.x, ed.y, ed.z, ed.w};            \
        float r0 = qb0, r1 = qb1;                                                   \
        _Pragma("unroll")                                                           \
        for (int j = 0; j < 16; ++j) {                                              \
            float2 w = *(const float2*)&W3s[j][d0];                                 \
            r0 = fmaf(ev[j], w.x, r0);                                              \
            r1 = fmaf(ev[j], w.y, r1);                                              \
        }                                                                           \
        float m0v = b2f((ushort_t)((PW) & 0xffff)) + r0;                            \
        float m1v = b2f((ushort_t)((PW) >> 16)) + r1;                               \
        float dd = (ES) - eigd;                                                     \
        float ad = fabsf(dd);                                                       \
        s0 += m0v; s1 += m1v;                                                       \
        ss0 = fmaf(m0v, m0v, ss0); ss1 = fmaf(m1v, m1v, ss1);                       \
        mx0 = fmaxf(mx0, m0v); mx1 = fmaxf(mx1, m1v);                               \
        mn0 = fminf(mn0, m0v); mn1 = fminf(mn1, m1v);                               \
        av0 = fmaf(m0v, ad, av0); av1 = fmaf(m1v, ad, av1);                         \
        dv0 = fmaf(m0v, dd, dv0); dv1 = fmaf(m1v, dd, dv1);                         \
        den += ad;                                                                  \
    }

    int i = off0;
    for (; i + 4 <= off1; i += 4) {
        int sv0 = se[i], sv1 = se[i + 1], sv2 = se[i + 2], sv3 = se[i + 3];
        float es0 = eig_src[i], es1 = eig_src[i + 1];
        float es2 = eig_src[i + 2], es3 = eig_src[i + 3];
        uint_t pw0 = *(const uint_t*)&PQ[(size_t)sv0 * 256 + d0];
        uint_t pw1 = *(const uint_t*)&PQ[(size_t)sv1 * 256 + d0];
        uint_t pw2 = *(const uint_t*)&PQ[(size_t)sv2 * 256 + d0];
        uint_t pw3 = *(const uint_t*)&PQ[(size_t)sv3 * 256 + d0];
        EDGE_BODY(i, es0, pw0);
        EDGE_BODY(i + 1, es1, pw1);
        EDGE_BODY(i + 2, es2, pw2);
        EDGE_BODY(i + 3, es3, pw3);
    }
    for (; i < off1; ++i) {
        int sv = se[i];
        float es = eig_src[i];
        uint_t pw = *(const uint_t*)&PQ[(size_t)sv * 256 + d0];
        EDGE_BODY(i, es, pw);
    }
#undef EDGE_BODY

    size_t xb = (size_t)n * 896 + 128;
    float2 hv = *(const float2*)&h[(size_t)n * 128 + d0];
    float o[12];
    if (deg > 0) {
        float inv = 1.f / (float)deg;
        float mean0 = s0 * inv, mean1 = s1 * inv;
        float var0 = fmaxf(ss0 * inv - mean0 * mean0, 0.f);
        float var1 = fmaxf(ss1 * inv - mean1 * mean1, 0.f);
        float sd0 = sqrtf(var0 + 1e-5f), sd1 = sqrtf(var1 + 1e-5f);
        float idn = 1.f / (den + 1e-8f);
        o[0] = mean0; o[1] = mean1; o[2] = mx0; o[3] = mx1; o[4] = mn0; o[5] = mn1;
        o[6] = sd0; o[7] = sd1; o[8] = av0 * idn; o[9] = av1 * idn;
        o[10] = dv0 * idn - hv.x; o[11] = dv1 * idn - hv.y;
    } else {
#pragma unroll
        for (int k = 0; k < 12; ++k) o[k] = 0.f;
    }
#pragma unroll
    for (int a = 0; a < 6; ++a) {
        uint_t w = (uint_t)f2b(o[2 * a]) | ((uint_t)f2b(o[2 * a + 1]) << 16);
        *(uint_t*)&X[xb + a * 128 + d0] = w;
    }
    if (lane == 0) {
        float degc = deg > 0 ? (float)deg : 1.f;
        float logd = logf(degc + 1.f);
        scal[n * 2] = logd * (1.f / 2.772588722239781f);
        scal[n * 2 + 1] = 2.772588722239781f / logd;
    }
}

// ---------------------------------------------------------------- epilogue
__global__ __launch_bounds__(256) void epilogue_kernel(
    const float* __restrict__ O3, const float* __restrict__ h,
    const float* __restrict__ snorm, const float* __restrict__ scal,
    const float* __restrict__ b_post, float* __restrict__ out, int Nn) {
    int g = blockIdx.x * 256 + threadIdx.x;
    if (g >= Nn * 32) return;
    int n = g >> 5, c4 = (g & 31) * 4;
    float a = scal[n * 2], b = scal[n * 2 + 1], sn = snorm[n];
    const float* base = O3 + (size_t)n * 384 + c4;
    float4 o1 = *(const float4*)base;
    float4 o2 = *(const float4*)(base + 128);
    float4 o3 = *(const float4*)(base + 256);
    float4 bp = *(const float4*)&b_post[c4];
    float4 hv = *(const float4*)&h[(size_t)n * 128 + c4];
    float4 r;
    r.x = fmaxf((o1.x + a * o2.x + b * o3.x + bp.x) * sn, 0.f) + hv.x;
    r.y = fmaxf((o1.y + a * o2.y + b * o3.y + bp.y) * sn, 0.f) + hv.y;
    r.z = fmaxf((o1.z + a * o2.z + b * o3.z + bp.z) * sn, 0.f) + hv.z;
    r.w = fmaxf((o1.w + a * o2.w + b * o3.w + bp.w) * sn, 0.f) + hv.w;
    *(float4*)&out[(size_t)n * 128 + c4] = r;
}

// ---------------------------------------------------------------- launch
extern "C" void kernel_launch(void* const* d_in, const int* in_sizes, int n_in,
                              void* d_out, int out_size, void* d_ws, size_t ws_size,
                              hipStream_t stream) {
    const float* h      = (const float*)d_in[0];
    const float* ef     = (const float*)d_in[1];
    const float* eig    = (const float*)d_in[2];
    const float* snorm  = (const float*)d_in[3];
    const int*   src    = (const int*)d_in[4];
    const int*   dst    = (const int*)d_in[5];
    const float* W_pre  = (const float*)d_in[6];
    const float* b_pre  = (const float*)d_in[7];
    const float* W_post = (const float*)d_in[8];
    const float* b_post = (const float*)d_in[9];
    int Nn = in_sizes[0] / 128;
    int E  = in_sizes[4];
    float* out = (float*)d_out;

    char* ws = (char*)d_ws;
    size_t off = 0;
    auto alloc = [&](size_t bytes) {
        size_t o = off;
        off = (off + bytes + 255) & ~(size_t)255;
        return o;
    };
    size_t o_counts  = alloc(((size_t)Nn + 1) * 4);
    size_t o_cursors = alloc((size_t)Nn * 4);
    size_t o_se      = alloc((size_t)E * 4);
    size_t o_esrc    = alloc((size_t)E * 4);
    size_t o_efp     = alloc((size_t)E * 16 * 4);
    size_t o_PQ      = alloc((size_t)Nn * 256 * 2);
    size_t o_X       = alloc((size_t)Nn * 896 * 2);
    size_t o_O3      = alloc((size_t)Nn * 384 * 4);
    size_t o_scal    = alloc((size_t)Nn * 2 * 4);
    size_t o_wb      = alloc(256 * 128 * 2);
    size_t o_wc      = alloc(384 * 896 * 2);
    (void)ws_size;

    int*      counts  = (int*)(ws + o_counts);
    int*      cursors = (int*)(ws + o_cursors);
    int*      se      = (int*)(ws + o_se);
    float*    esrc    = (float*)(ws + o_esrc);
    float*    efp     = (float*)(ws + o_efp);
    ushort_t* PQ      = (ushort_t*)(ws + o_PQ);
    ushort_t* X       = (ushort_t*)(ws + o_X);
    float*    O3      = (float*)(ws + o_O3);
    float*    scal    = (float*)(ws + o_scal);
    ushort_t* WbT     = (ushort_t*)(ws + o_wb);
    ushort_t* WcT     = (ushort_t*)(ws + o_wc);

    zero_kernel<<<(Nn + 1 + 255) / 256, 256, 0, stream>>>(counts, Nn + 1);
    pack_wb<<<(256 * 128 + 255) / 256, 256, 0, stream>>>(W_pre, WbT);
    pack_wc<<<(384 * 896 + 255) / 256, 256, 0, stream>>>(W_post, WcT);
    conv_h<<<(Nn * 32 + 255) / 256, 256, 0, stream>>>(h, X, Nn);
    hist_kernel<<<(E + 255) / 256, 256, 0, stream>>>(dst, counts, E);
    scan_kernel<<<1, 1024, 0, stream>>>(counts, cursors, Nn);
    scatter_kernel<<<(E + 255) / 256, 256, 0, stream>>>(dst, src, eig, ef, cursors,
                                                        se, esrc, efp, E);

    int mt = (Nn + 127) / 128;
    gemm_bt<1><<<mt * 2, 256, 0, stream>>>(X, 896, WbT, 128, (void*)PQ, 256, Nn, 128, 2);

    agg_kernel<<<(Nn + 3) / 4, 256, 0, stream>>>(PQ, X, efp, esrc, se, counts, eig, h,
                                                 W_pre, b_pre, scal, Nn);

    gemm_bt<0><<<mt * 3, 256, 0, stream>>>(X, 896, WcT, 896, (void*)O3, 384, Nn, 896, 3);

    epilogue_kernel<<<(Nn * 32 + 255) / 256, 256, 0, stream>>>(O3, h, snorm, scal, b_post,
                                                               out, Nn);
}

// Round 3
// 452.664 us; speedup vs baseline: 1.0181x; 1.0181x over previous
//
#include <hip/hip_runtime.h>
#include <hip/hip_bf16.h>
#include <math.h>

typedef __attribute__((ext_vector_type(4))) float f32x4;
typedef __attribute__((ext_vector_type(8))) short short8;
typedef unsigned short ushort_t;
typedef unsigned int uint_t;

__device__ __forceinline__ float b2f(unsigned short u) {
    unsigned int v = ((unsigned int)u) << 16;
    return __uint_as_float(v);
}
__device__ __forceinline__ unsigned short f2b(float f) {
    unsigned int x = __float_as_uint(f);
    unsigned int r = (x + 0x7fffu + ((x >> 16) & 1u)) >> 16;
    return (unsigned short)r;
}

// ---------------------------------------------------------------- small prep
__global__ void zero_kernel(int* p, int n) {
    int i = blockIdx.x * 256 + threadIdx.x;
    if (i < n) p[i] = 0;
}

// WbT[n][k] (bf16, [256,128]) = B^T of [W1|W2] so PQ = h @ [W1|W2]
__global__ void pack_wb(const float* __restrict__ W_pre, ushort_t* __restrict__ WbT) {
    int i = blockIdx.x * 256 + threadIdx.x;
    if (i >= 256 * 128) return;
    int nn = i >> 7, k = i & 127;
    float v = (nn < 128) ? W_pre[k * 128 + nn] : W_pre[(128 + k) * 128 + (nn - 128)];
    WbT[i] = f2b(v);
}

// WcT[n][k] (bf16, [384,896]): block matrix [[Wp0,0,0],[Wp1,Wp2,Wp3]] transposed
__global__ void pack_wc(const float* __restrict__ W_post, ushort_t* __restrict__ WcT) {
    int i = blockIdx.x * 256 + threadIdx.x;
    if (i >= 384 * 896) return;
    int nn = i / 896, k = i % 896;
    float v;
    if (k < 128) {
        v = (nn < 128) ? W_post[k * 128 + nn] : 0.f;
    } else {
        int ka = k - 128;
        if (nn < 128)      v = W_post[(128 + ka) * 128 + nn];
        else if (nn < 256) v = W_post[(896 + ka) * 128 + (nn - 128)];
        else               v = W_post[(1664 + ka) * 128 + (nn - 256)];
    }
    WcT[i] = f2b(v);
}

// X[:,0:128] = bf16(h)   (X row stride 896)
__global__ void conv_h(const float* __restrict__ h, ushort_t* __restrict__ X, int Nn) {
    int g = blockIdx.x * 256 + threadIdx.x;
    if (g >= Nn * 32) return;
    int n = g >> 5, c4 = (g & 31) * 4;
    float4 hv = *(const float4*)&h[(size_t)n * 128 + c4];
    ushort4 o;
    o.x = f2b(hv.x); o.y = f2b(hv.y); o.z = f2b(hv.z); o.w = f2b(hv.w);
    *(ushort4*)&X[(size_t)n * 896 + c4] = o;
}

// ---------------------------------------------------------------- CSR build
__global__ void hist_kernel(const int* __restrict__ dst, int* __restrict__ counts, int E) {
    int i = blockIdx.x * 256 + threadIdx.x;
    if (i < E) atomicAdd(&counts[dst[i]], 1);
}

// single block exclusive scan over counts[0..Nn-1] -> offsets (in place) + cursors
__global__ __launch_bounds__(1024) void scan_kernel(int* __restrict__ counts,
                                                    int* __restrict__ cursors, int Nn) {
    __shared__ int part[1024];
    int t = threadIdx.x;
    int base = t * 40;
    int loc[40];
    int s = 0;
#pragma unroll
    for (int i = 0; i < 40; ++i) {
        int idx = base + i;
        int v = (idx < Nn) ? counts[idx] : 0;
        loc[i] = s; s += v;
    }
    part[t] = s;
    __syncthreads();
    for (int off = 1; off < 1024; off <<= 1) {
        int v = part[t];
        int u = (t >= off) ? part[t - off] : 0;
        __syncthreads();
        part[t] = v + u;
        __syncthreads();
    }
    int pre = (t > 0) ? part[t - 1] : 0;
#pragma unroll
    for (int i = 0; i < 40; ++i) {
        int idx = base + i;
        if (idx < Nn) { int o = pre + loc[i]; counts[idx] = o; cursors[idx] = o; }
    }
    if (t == 1023) counts[Nn] = part[1023];
}

// scatter: pos[eid] = CSR slot; esrc[slot] = eig_src (4B scatters only)
__global__ void scatter_kernel(const int* __restrict__ dst, const int* __restrict__ src,
                               const float* __restrict__ eig, int* __restrict__ cursors,
                               int* __restrict__ pos, float* __restrict__ esrc, int E) {
    int i = blockIdx.x * 256 + threadIdx.x;
    if (i < E) {
        int v = dst[i];
        int p = atomicAdd(&cursors[v], 1);
        pos[i] = p;
        esrc[p] = eig[src[i] * 2 + 1];
    }
}

// ---------------------------------------------------------------- bf16 MFMA GEMM (B^T)
// C[M,N] = A[M,K](bf16,lda) @ Bt[N,K]^T(bf16,ldb=K).  128x128 tile, BK=64, 4 waves.
// 1-D grid; bijective XCD remap, n-tile fastest => A-panel shared within an XCD's L2.
template <int OUT_BF16>
__global__ __launch_bounds__(256) void gemm_bt(const ushort_t* __restrict__ A, int lda,
                                               const ushort_t* __restrict__ Bt, int ldb,
                                               void* __restrict__ Cv, int ldc,
                                               int M, int K, int NT) {
    __shared__ ushort_t ldsbuf[2 * 128 * 64];
    const int tid = threadIdx.x, wid = tid >> 6, lane = tid & 63;
    int nwg = gridDim.x;
    int orig = blockIdx.x;
    int q8 = nwg >> 3, r8 = nwg & 7;
    int xcd = orig & 7, local = orig >> 3;
    int wg = (xcd < r8 ? xcd * (q8 + 1) : r8 * (q8 + 1) + (xcd - r8) * q8) + local;
    const int m0 = (wg / NT) * 128, n0 = (wg % NT) * 128;
    f32x4 acc[4][4] = {};
    const int wrow = (wid >> 1) * 64, wcol = (wid & 1) * 64;

    for (int kt = 0; kt < K; kt += 64) {
#pragma unroll
        for (int rnd = 0; rnd < 4; ++rnd) {
            int libase = rnd * 256 + wid * 64;
            {   // A tile: chunk li = r*8 + (c ^ (r&7)), 16B chunks
                int lc = libase + lane;
                int r = lc >> 3, cs = lc & 7;
                int c = cs ^ (r & 7);
                int row = m0 + r; row = row < M ? row : M - 1;
                const ushort_t* g = A + (size_t)row * lda + (kt + c * 8);
                __builtin_amdgcn_global_load_lds(
                    (const __attribute__((address_space(1))) unsigned int*)g,
                    (__attribute__((address_space(3))) unsigned int*)&ldsbuf[(size_t)libase * 8],
                    16, 0, 0);
            }
            {   // B tile (rows of Bt)
                int lc = libase + lane;
                int r = lc >> 3, cs = lc & 7;
                int c = cs ^ (r & 7);
                const ushort_t* g = Bt + (size_t)(n0 + r) * ldb + (kt + c * 8);
                __builtin_amdgcn_global_load_lds(
                    (const __attribute__((address_space(1))) unsigned int*)g,
                    (__attribute__((address_space(3))) unsigned int*)&ldsbuf[8192 + (size_t)libase * 8],
                    16, 0, 0);
            }
        }
        __syncthreads();
#pragma unroll
        for (int kk = 0; kk < 2; ++kk) {
            short8 af[4], bfr[4];
#pragma unroll
            for (int f = 0; f < 4; ++f) {
                int r = wrow + f * 16 + (lane & 15);
                int c16 = kk * 4 + (lane >> 4);
                int ch = r * 8 + (c16 ^ (r & 7));
                af[f] = *(const short8*)&ldsbuf[ch * 8];
            }
#pragma unroll
            for (int f = 0; f < 4; ++f) {
                int r = wcol + f * 16 + (lane & 15);
                int c16 = kk * 4 + (lane >> 4);
                int ch = r * 8 + (c16 ^ (r & 7));
                bfr[f] = *(const short8*)&ldsbuf[8192 + ch * 8];
            }
#pragma unroll
            for (int i = 0; i < 4; ++i)
#pragma unroll
                for (int j = 0; j < 4; ++j)
                    acc[i][j] = __builtin_amdgcn_mfma_f32_16x16x32_bf16(af[i], bfr[j], acc[i][j], 0, 0, 0);
        }
        __syncthreads();
    }
#pragma unroll
    for (int i = 0; i < 4; ++i)
#pragma unroll
        for (int j = 0; j < 4; ++j)
#pragma unroll
            for (int q = 0; q < 4; ++q) {
                int row = m0 + wrow + i * 16 + (lane >> 4) * 4 + q;
                int col = n0 + wcol + j * 16 + (lane & 15);
                if (row < M) {
                    if (OUT_BF16) ((ushort_t*)Cv)[(size_t)row * ldc + col] = f2b(acc[i][j][q]);
                    else          ((float*)Cv)[(size_t)row * ldc + col] = acc[i][j][q];
                }
            }
}

// ---------------------------------------------------------------- edge messages
// Edge-parallel, original edge order: all inputs are coalesced streams except the
// two PQ row gathers (L2/L3-resident). Writes bf16 m-row to CSR slot pos[e].
__global__ __launch_bounds__(256) void medge_kernel(
    const ushort_t* __restrict__ PQ, const int* __restrict__ src,
    const int* __restrict__ dst, const int* __restrict__ pos,
    const float* __restrict__ ef, const float* __restrict__ W_pre,
    const float* __restrict__ b_pre, ushort_t* __restrict__ m_perm, int E) {
    __shared__ float W3s[16][128];
    __shared__ float bps[128];
    int tid = threadIdx.x;
    for (int i = tid; i < 2048; i += 256) {
        int j = i >> 7, c = i & 127;
        W3s[j][c] = W_pre[(256 + j) * 128 + c];
    }
    if (tid < 128) bps[tid] = b_pre[tid];
    __syncthreads();
    int wid = tid >> 6, lane = tid & 63, d0 = lane * 2;
    float bp0 = bps[d0], bp1 = bps[d0 + 1];
    int base = (blockIdx.x * 4 + wid) * 16;
    int end = base + 16; if (end > E) end = E;
    for (int e = base; e < end; ++e) {
        int sv = src[e], dv = dst[e], p = pos[e];
        const float4* ep = (const float4*)(ef + (size_t)e * 16);
        float4 ea = ep[0], eb = ep[1], ec = ep[2], ed = ep[3];
        uint_t pw = *(const uint_t*)&PQ[(size_t)sv * 256 + d0];
        uint_t qw = *(const uint_t*)&PQ[(size_t)dv * 256 + 128 + d0];
        float ev[16] = {ea.x, ea.y, ea.z, ea.w, eb.x, eb.y, eb.z, eb.w,
                        ec.x, ec.y, ec.z, ec.w, ed.x, ed.y, ed.z, ed.w};
        float r0 = b2f((ushort_t)(pw & 0xffff)) + b2f((ushort_t)(qw & 0xffff)) + bp0;
        float r1 = b2f((ushort_t)(pw >> 16)) + b2f((ushort_t)(qw >> 16)) + bp1;
#pragma unroll
        for (int j = 0; j < 16; ++j) {
            float2 w = *(const float2*)&W3s[j][d0];
            r0 = fmaf(ev[j], w.x, r0);
            r1 = fmaf(ev[j], w.y, r1);
        }
        uint_t w = (uint_t)f2b(r0) | ((uint_t)f2b(r1) << 16);
        *(uint_t*)&m_perm[(size_t)p * 128 + d0] = w;
    }
}

// ---------------------------------------------------------------- aggregation
// one wave per node; pure streaming reads of m_perm rows + esrc.
__global__ __launch_bounds__(256) void agg_kernel(
    const ushort_t* __restrict__ m_perm, ushort_t* __restrict__ X,
    const float* __restrict__ esrc, const int* __restrict__ offs,
    const float* __restrict__ eig, const float* __restrict__ h,
    float* __restrict__ scal, int Nn) {
    int tid = threadIdx.x, wid = tid >> 6, lane = tid & 63;
    int n = blockIdx.x * 4 + wid;
    if (n >= Nn) return;
    int off0 = offs[n], off1 = offs[n + 1];
    int deg = off1 - off0;
    int d0 = lane * 2;
    float eigd = eig[n * 2 + 1];

    float s0 = 0, s1 = 0, ss0 = 0, ss1 = 0, av0 = 0, av1 = 0, dv0 = 0, dv1 = 0, den = 0;
    float mx0 = -1e30f, mx1 = -1e30f, mn0 = 1e30f, mn1 = 1e30f;

#define EDGE_BODY(MW, ES)                                                           \
    {                                                                               \
        float m0v = b2f((ushort_t)((MW) & 0xffff));                                 \
        float m1v = b2f((ushort_t)((MW) >> 16));                                    \
        float dd = (ES) - eigd;                                                     \
        float ad = fabsf(dd);                                                       \
        s0 += m0v; s1 += m1v;                                                       \
        ss0 = fmaf(m0v, m0v, ss0); ss1 = fmaf(m1v, m1v, ss1);                       \
        mx0 = fmaxf(mx0, m0v); mx1 = fmaxf(mx1, m1v);                               \
        mn0 = fminf(mn0, m0v); mn1 = fminf(mn1, m1v);                               \
        av0 = fmaf(m0v, ad, av0); av1 = fmaf(m1v, ad, av1);                         \
        dv0 = fmaf(m0v, dd, dv0); dv1 = fmaf(m1v, dd, dv1);                         \
        den += ad;                                                                  \
    }

    int p = off0;
    for (; p + 4 <= off1; p += 4) {
        uint_t mw0 = *(const uint_t*)&m_perm[(size_t)p * 128 + d0];
        uint_t mw1 = *(const uint_t*)&m_perm[(size_t)(p + 1) * 128 + d0];
        uint_t mw2 = *(const uint_t*)&m_perm[(size_t)(p + 2) * 128 + d0];
        uint_t mw3 = *(const uint_t*)&m_perm[(size_t)(p + 3) * 128 + d0];
        float es0 = esrc[p], es1 = esrc[p + 1], es2 = esrc[p + 2], es3 = esrc[p + 3];
        EDGE_BODY(mw0, es0);
        EDGE_BODY(mw1, es1);
        EDGE_BODY(mw2, es2);
        EDGE_BODY(mw3, es3);
    }
    for (; p < off1; ++p) {
        uint_t mw = *(const uint_t*)&m_perm[(size_t)p * 128 + d0];
        float es = esrc[p];
        EDGE_BODY(mw, es);
    }
#undef EDGE_BODY

    size_t xb = (size_t)n * 896 + 128;
    float2 hv = *(const float2*)&h[(size_t)n * 128 + d0];
    float o[12];
    if (deg > 0) {
        float inv = 1.f / (float)deg;
        float mean0 = s0 * inv, mean1 = s1 * inv;
        float var0 = fmaxf(ss0 * inv - mean0 * mean0, 0.f);
        float var1 = fmaxf(ss1 * inv - mean1 * mean1, 0.f);
        float sd0 = sqrtf(var0 + 1e-5f), sd1 = sqrtf(var1 + 1e-5f);
        float idn = 1.f / (den + 1e-8f);
        o[0] = mean0; o[1] = mean1; o[2] = mx0; o[3] = mx1; o[4] = mn0; o[5] = mn1;
        o[6] = sd0; o[7] = sd1; o[8] = av0 * idn; o[9] = av1 * idn;
        o[10] = dv0 * idn - hv.x; o[11] = dv1 * idn - hv.y;
    } else {
#pragma unroll
        for (int k = 0; k < 12; ++k) o[k] = 0.f;
    }
#pragma unroll
    for (int a = 0; a < 6; ++a) {
        uint_t w = (uint_t)f2b(o[2 * a]) | ((uint_t)f2b(o[2 * a + 1]) << 16);
        *(uint_t*)&X[xb + a * 128 + d0] = w;
    }
    if (lane == 0) {
        float degc = deg > 0 ? (float)deg : 1.f;
        float logd = logf(degc + 1.f);
        scal[n * 2] = logd * (1.f / 2.772588722239781f);
        scal[n * 2 + 1] = 2.772588722239781f / logd;
    }
}

// ---------------------------------------------------------------- epilogue
__global__ __launch_bounds__(256) void epilogue_kernel(
    const float* __restrict__ O3, const float* __restrict__ h,
    const float* __restrict__ snorm, const float* __restrict__ scal,
    const float* __restrict__ b_post, float* __restrict__ out, int Nn) {
    int g = blockIdx.x * 256 + threadIdx.x;
    if (g >= Nn * 32) return;
    int n = g >> 5, c4 = (g & 31) * 4;
    float a = scal[n * 2], b = scal[n * 2 + 1], sn = snorm[n];
    const float* base = O3 + (size_t)n * 384 + c4;
    float4 o1 = *(const float4*)base;
    float4 o2 = *(const float4*)(base + 128);
    float4 o3 = *(const float4*)(base + 256);
    float4 bp = *(const float4*)&b_post[c4];
    float4 hv = *(const float4*)&h[(size_t)n * 128 + c4];
    float4 r;
    r.x = fmaxf((o1.x + a * o2.x + b * o3.x + bp.x) * sn, 0.f) + hv.x;
    r.y = fmaxf((o1.y + a * o2.y + b * o3.y + bp.y) * sn, 0.f) + hv.y;
    r.z = fmaxf((o1.z + a * o2.z + b * o3.z + bp.z) * sn, 0.f) + hv.z;
    r.w = fmaxf((o1.w + a * o2.w + b * o3.w + bp.w) * sn, 0.f) + hv.w;
    *(float4*)&out[(size_t)n * 128 + c4] = r;
}

// ---------------------------------------------------------------- launch
extern "C" void kernel_launch(void* const* d_in, const int* in_sizes, int n_in,
                              void* d_out, int out_size, void* d_ws, size_t ws_size,
                              hipStream_t stream) {
    const float* h      = (const float*)d_in[0];
    const float* ef     = (const float*)d_in[1];
    const float* eig    = (const float*)d_in[2];
    const float* snorm  = (const float*)d_in[3];
    const int*   src    = (const int*)d_in[4];
    const int*   dst    = (const int*)d_in[5];
    const float* W_pre  = (const float*)d_in[6];
    const float* b_pre  = (const float*)d_in[7];
    const float* W_post = (const float*)d_in[8];
    const float* b_post = (const float*)d_in[9];
    int Nn = in_sizes[0] / 128;
    int E  = in_sizes[4];
    float* out = (float*)d_out;

    char* ws = (char*)d_ws;
    size_t off = 0;
    auto alloc = [&](size_t bytes) {
        size_t o = off;
        off = (off + bytes + 255) & ~(size_t)255;
        return o;
    };
    size_t o_counts  = alloc(((size_t)Nn + 1) * 4);
    size_t o_cursors = alloc((size_t)Nn * 4);
    size_t o_pos     = alloc((size_t)E * 4);
    size_t o_esrc    = alloc((size_t)E * 4);
    size_t o_PQ      = alloc((size_t)Nn * 256 * 2);
    size_t o_X       = alloc((size_t)Nn * 896 * 2);
    size_t o_m       = alloc((size_t)E * 128 * 2);   // m_perm; O3 aliases (dead after agg)
    size_t o_scal    = alloc((size_t)Nn * 2 * 4);
    size_t o_wb      = alloc(256 * 128 * 2);
    size_t o_wc      = alloc(384 * 896 * 2);
    (void)ws_size;

    int*      counts  = (int*)(ws + o_counts);
    int*      cursors = (int*)(ws + o_cursors);
    int*      pos     = (int*)(ws + o_pos);
    float*    esrc    = (float*)(ws + o_esrc);
    ushort_t* PQ      = (ushort_t*)(ws + o_PQ);
    ushort_t* X       = (ushort_t*)(ws + o_X);
    ushort_t* m_perm  = (ushort_t*)(ws + o_m);
    float*    O3      = (float*)(ws + o_m);          // alias: post-GEMM runs after agg
    float*    scal    = (float*)(ws + o_scal);
    ushort_t* WbT     = (ushort_t*)(ws + o_wb);
    ushort_t* WcT     = (ushort_t*)(ws + o_wc);

    zero_kernel<<<(Nn + 1 + 255) / 256, 256, 0, stream>>>(counts, Nn + 1);
    pack_wb<<<(256 * 128 + 255) / 256, 256, 0, stream>>>(W_pre, WbT);
    pack_wc<<<(384 * 896 + 255) / 256, 256, 0, stream>>>(W_post, WcT);
    conv_h<<<(Nn * 32 + 255) / 256, 256, 0, stream>>>(h, X, Nn);
    hist_kernel<<<(E + 255) / 256, 256, 0, stream>>>(dst, counts, E);
    scan_kernel<<<1, 1024, 0, stream>>>(counts, cursors, Nn);
    scatter_kernel<<<(E + 255) / 256, 256, 0, stream>>>(dst, src, eig, cursors,
                                                        pos, esrc, E);

    int mt = (Nn + 127) / 128;
    gemm_bt<1><<<mt * 2, 256, 0, stream>>>(X, 896, WbT, 128, (void*)PQ, 256, Nn, 128, 2);

    medge_kernel<<<(E + 63) / 64, 256, 0, stream>>>(PQ, src, dst, pos, ef, W_pre, b_pre,
                                                    m_perm, E);

    agg_kernel<<<(Nn + 3) / 4, 256, 0, stream>>>(m_perm, X, esrc, counts, eig, h,
                                                 scal, Nn);

    gemm_bt<0><<<mt * 3, 256, 0, stream>>>(X, 896, WcT, 896, (void*)O3, 384, Nn, 896, 3);

    epilogue_kernel<<<(Nn * 32 + 255) / 256, 256, 0, stream>>>(O3, h, snorm, scal, b_post,
                                                               out, Nn);
}

// Round 5
// 355.732 us; speedup vs baseline: 1.2955x; 1.2725x over previous
//
#include <hip/hip_runtime.h>
#include <hip/hip_bf16.h>
#include <math.h>

typedef __attribute__((ext_vector_type(4))) float f32x4;
typedef __attribute__((ext_vector_type(8))) short short8;
typedef unsigned short ushort_t;
typedef unsigned int uint_t;

__device__ __forceinline__ float b2f(unsigned short u) {
    unsigned int v = ((unsigned int)u) << 16;
    return __uint_as_float(v);
}
__device__ __forceinline__ unsigned short f2b(float f) {
    unsigned int x = __float_as_uint(f);
    unsigned int r = (x + 0x7fffu + ((x >> 16) & 1u)) >> 16;
    return (unsigned short)r;
}

// ---------------------------------------------------------------- small prep
__global__ void zero_kernel(int* p, int n) {
    int i = blockIdx.x * 256 + threadIdx.x;
    if (i < n) p[i] = 0;
}

// WbT[n][k] (bf16, [256,128]) = B^T of [W1|W2] so PQ = h @ [W1|W2]
__global__ void pack_wb(const float* __restrict__ W_pre, ushort_t* __restrict__ WbT) {
    int i = blockIdx.x * 256 + threadIdx.x;
    if (i >= 256 * 128) return;
    int nn = i >> 7, k = i & 127;
    float v = (nn < 128) ? W_pre[k * 128 + nn] : W_pre[(128 + k) * 128 + (nn - 128)];
    WbT[i] = f2b(v);
}

// WcT[n][k] (bf16, [384,896]): block matrix [[Wp0,0,0],[Wp1,Wp2,Wp3]] transposed
__global__ void pack_wc(const float* __restrict__ W_post, ushort_t* __restrict__ WcT) {
    int i = blockIdx.x * 256 + threadIdx.x;
    if (i >= 384 * 896) return;
    int nn = i / 896, k = i % 896;
    float v;
    if (k < 128) {
        v = (nn < 128) ? W_post[k * 128 + nn] : 0.f;
    } else {
        int ka = k - 128;
        if (nn < 128)      v = W_post[(128 + ka) * 128 + nn];
        else if (nn < 256) v = W_post[(896 + ka) * 128 + (nn - 128)];
        else               v = W_post[(1664 + ka) * 128 + (nn - 256)];
    }
    WcT[i] = f2b(v);
}

// X[:,0:128] = bf16(h)   (X row stride 896)
__global__ void conv_h(const float* __restrict__ h, ushort_t* __restrict__ X, int Nn) {
    int g = blockIdx.x * 256 + threadIdx.x;
    if (g >= Nn * 32) return;
    int n = g >> 5, c4 = (g & 31) * 4;
    float4 hv = *(const float4*)&h[(size_t)n * 128 + c4];
    ushort4 o;
    o.x = f2b(hv.x); o.y = f2b(hv.y); o.z = f2b(hv.z); o.w = f2b(hv.w);
    *(ushort4*)&X[(size_t)n * 896 + c4] = o;
}

// ---------------------------------------------------------------- CSR build
__global__ void hist_kernel(const int* __restrict__ dst, int* __restrict__ counts, int E) {
    int i = blockIdx.x * 256 + threadIdx.x;
    if (i < E) atomicAdd(&counts[dst[i]], 1);
}

// single block exclusive scan over counts[0..Nn-1] -> offsets (in place) + cursors
__global__ __launch_bounds__(1024) void scan_kernel(int* __restrict__ counts,
                                                    int* __restrict__ cursors, int Nn) {
    __shared__ int part[1024];
    int t = threadIdx.x;
    int base = t * 40;
    int loc[40];
    int s = 0;
#pragma unroll
    for (int i = 0; i < 40; ++i) {
        int idx = base + i;
        int v = (idx < Nn) ? counts[idx] : 0;
        loc[i] = s; s += v;
    }
    part[t] = s;
    __syncthreads();
    for (int off = 1; off < 1024; off <<= 1) {
        int v = part[t];
        int u = (t >= off) ? part[t - off] : 0;
        __syncthreads();
        part[t] = v + u;
        __syncthreads();
    }
    int pre = (t > 0) ? part[t - 1] : 0;
#pragma unroll
    for (int i = 0; i < 40; ++i) {
        int idx = base + i;
        if (idx < Nn) { int o = pre + loc[i]; counts[idx] = o; cursors[idx] = o; }
    }
    if (t == 1023) counts[Nn] = part[1023];
}

// scatter: one aligned 16B record per CSR slot: {src, eid, eig_src_bits, 0}
__global__ void scatter_kernel(const int* __restrict__ dst, const int* __restrict__ src,
                               const float* __restrict__ eig, int* __restrict__ cursors,
                               int4* __restrict__ esl, int E) {
    int i = blockIdx.x * 256 + threadIdx.x;
    if (i < E) {
        int v = dst[i];
        int p = atomicAdd(&cursors[v], 1);
        int s = src[i];
        esl[p] = make_int4(s, i, __float_as_int(eig[s * 2 + 1]), 0);
    }
}

// ---------------------------------------------------------------- bf16 MFMA GEMM (B^T)
// C[M,N] = A[M,K](bf16,lda) @ Bt[N,K]^T(bf16,ldb=K).  128x128 tile, BK=64, 4 waves.
// 1-D grid; bijective XCD remap, n-tile fastest => A-panel shared within an XCD's L2.
template <int OUT_BF16>
__global__ __launch_bounds__(256) void gemm_bt(const ushort_t* __restrict__ A, int lda,
                                               const ushort_t* __restrict__ Bt, int ldb,
                                               void* __restrict__ Cv, int ldc,
                                               int M, int K, int NT) {
    __shared__ ushort_t ldsbuf[2 * 128 * 64];
    const int tid = threadIdx.x, wid = tid >> 6, lane = tid & 63;
    int nwg = gridDim.x;
    int orig = blockIdx.x;
    int q8 = nwg >> 3, r8 = nwg & 7;
    int xcd = orig & 7, local = orig >> 3;
    int wg = (xcd < r8 ? xcd * (q8 + 1) : r8 * (q8 + 1) + (xcd - r8) * q8) + local;
    const int m0 = (wg / NT) * 128, n0 = (wg % NT) * 128;
    f32x4 acc[4][4] = {};
    const int wrow = (wid >> 1) * 64, wcol = (wid & 1) * 64;

    for (int kt = 0; kt < K; kt += 64) {
#pragma unroll
        for (int rnd = 0; rnd < 4; ++rnd) {
            int libase = rnd * 256 + wid * 64;
            {   // A tile: chunk li = r*8 + (c ^ (r&7)), 16B chunks
                int lc = libase + lane;
                int r = lc >> 3, cs = lc & 7;
                int c = cs ^ (r & 7);
                int row = m0 + r; row = row < M ? row : M - 1;
                const ushort_t* g = A + (size_t)row * lda + (kt + c * 8);
                __builtin_amdgcn_global_load_lds(
                    (const __attribute__((address_space(1))) unsigned int*)g,
                    (__attribute__((address_space(3))) unsigned int*)&ldsbuf[(size_t)libase * 8],
                    16, 0, 0);
            }
            {   // B tile (rows of Bt)
                int lc = libase + lane;
                int r = lc >> 3, cs = lc & 7;
                int c = cs ^ (r & 7);
                const ushort_t* g = Bt + (size_t)(n0 + r) * ldb + (kt + c * 8);
                __builtin_amdgcn_global_load_lds(
                    (const __attribute__((address_space(1))) unsigned int*)g,
                    (__attribute__((address_space(3))) unsigned int*)&ldsbuf[8192 + (size_t)libase * 8],
                    16, 0, 0);
            }
        }
        __syncthreads();
#pragma unroll
        for (int kk = 0; kk < 2; ++kk) {
            short8 af[4], bfr[4];
#pragma unroll
            for (int f = 0; f < 4; ++f) {
                int r = wrow + f * 16 + (lane & 15);
                int c16 = kk * 4 + (lane >> 4);
                int ch = r * 8 + (c16 ^ (r & 7));
                af[f] = *(const short8*)&ldsbuf[ch * 8];
            }
#pragma unroll
            for (int f = 0; f < 4; ++f) {
                int r = wcol + f * 16 + (lane & 15);
                int c16 = kk * 4 + (lane >> 4);
                int ch = r * 8 + (c16 ^ (r & 7));
                bfr[f] = *(const short8*)&ldsbuf[8192 + ch * 8];
            }
#pragma unroll
            for (int i = 0; i < 4; ++i)
#pragma unroll
                for (int j = 0; j < 4; ++j)
                    acc[i][j] = __builtin_amdgcn_mfma_f32_16x16x32_bf16(af[i], bfr[j], acc[i][j], 0, 0, 0);
        }
        __syncthreads();
    }
#pragma unroll
    for (int i = 0; i < 4; ++i)
#pragma unroll
        for (int j = 0; j < 4; ++j)
#pragma unroll
            for (int q = 0; q < 4; ++q) {
                int row = m0 + wrow + i * 16 + (lane >> 4) * 4 + q;
                int col = n0 + wcol + j * 16 + (lane & 15);
                if (row < M) {
                    if (OUT_BF16) ((ushort_t*)Cv)[(size_t)row * ldc + col] = f2b(acc[i][j][q]);
                    else          ((float*)Cv)[(size_t)row * ldc + col] = acc[i][j][q];
                }
            }
}

// ---------------------------------------------------------------- fused agg
// one wave per node. Edge chunks of 4: uniform 16B record loads, then 4 PQ
// gathers + 16 ef float4 loads all independently in flight, then 4 bodies.
__global__ __launch_bounds__(256) void agg_fused(
    const ushort_t* __restrict__ PQ, ushort_t* __restrict__ X,
    const int4* __restrict__ esl, const int* __restrict__ offs,
    const float* __restrict__ eig, const float* __restrict__ h,
    const float* __restrict__ ef, const float* __restrict__ W_pre,
    const float* __restrict__ b_pre, float* __restrict__ scal, int Nn) {
    __shared__ float W3s[16][128];
    __shared__ float bps[128];
    int tid = threadIdx.x;
    for (int i = tid; i < 2048; i += 256) {
        int j = i >> 7, c = i & 127;
        W3s[j][c] = W_pre[(256 + j) * 128 + c];
    }
    if (tid < 128) bps[tid] = b_pre[tid];
    __syncthreads();
    int wid = tid >> 6, lane = tid & 63;
    int n = blockIdx.x * 4 + wid;
    if (n >= Nn) return;
    int off0 = offs[n], off1 = offs[n + 1];
    int deg = off1 - off0;
    int d0 = lane * 2;

    uint_t qw = *(const uint_t*)&PQ[(size_t)n * 256 + 128 + d0];
    float qb0 = b2f((ushort_t)(qw & 0xffff)) + bps[d0];
    float qb1 = b2f((ushort_t)(qw >> 16)) + bps[d0 + 1];
    float eigd = eig[n * 2 + 1];

    float s0 = 0, s1 = 0, ss0 = 0, ss1 = 0, av0 = 0, av1 = 0, dv0 = 0, dv1 = 0, den = 0;
    float mx0 = -1e30f, mx1 = -1e30f, mn0 = 1e30f, mn1 = 1e30f;

#define BODY(PW, EA, EB, EC, ED, ESB)                                               \
    {                                                                               \
        float ev[16] = {(EA).x, (EA).y, (EA).z, (EA).w, (EB).x, (EB).y, (EB).z,     \
                        (EB).w, (EC).x, (EC).y, (EC).z, (EC).w, (ED).x, (ED).y,     \
                        (ED).z, (ED).w};                                            \
        float mr0 = qb0, mr1 = qb1;                                                 \
        _Pragma("unroll")                                                           \
        for (int j = 0; j < 16; ++j) {                                              \
            float2 w = *(const float2*)&W3s[j][d0];                                 \
            mr0 = fmaf(ev[j], w.x, mr0);                                            \
            mr1 = fmaf(ev[j], w.y, mr1);                                            \
        }                                                                           \
        float m0v = b2f((ushort_t)((PW) & 0xffff)) + mr0;                           \
        float m1v = b2f((ushort_t)((PW) >> 16)) + mr1;                              \
        float dd = __int_as_float(ESB) - eigd;                                      \
        float ad = fabsf(dd);                                                       \
        s0 += m0v; s1 += m1v;                                                       \
        ss0 = fmaf(m0v, m0v, ss0); ss1 = fmaf(m1v, m1v, ss1);                       \
        mx0 = fmaxf(mx0, m0v); mx1 = fmaxf(mx1, m1v);                               \
        mn0 = fminf(mn0, m0v); mn1 = fminf(mn1, m1v);                               \
        av0 = fmaf(m0v, ad, av0); av1 = fmaf(m1v, ad, av1);                         \
        dv0 = fmaf(m0v, dd, dv0); dv1 = fmaf(m1v, dd, dv1);                         \
        den += ad;                                                                  \
    }

    for (int p = off0; p < off1; p += 4) {
        int lim = off1 - 1;
        int p1 = p + 1 < lim ? p + 1 : lim;
        int p2 = p + 2 < lim ? p + 2 : lim;
        int p3 = p + 3 < lim ? p + 3 : lim;
        int4 rc0 = esl[p], rc1 = esl[p1], rc2 = esl[p2], rc3 = esl[p3];
        uint_t pw0 = *(const uint_t*)&PQ[(size_t)rc0.x * 256 + d0];
        uint_t pw1 = *(const uint_t*)&PQ[(size_t)rc1.x * 256 + d0];
        uint_t pw2 = *(const uint_t*)&PQ[(size_t)rc2.x * 256 + d0];
        uint_t pw3 = *(const uint_t*)&PQ[(size_t)rc3.x * 256 + d0];
        const float4* e0 = (const float4*)(ef + (size_t)rc0.y * 16);
        const float4* e1 = (const float4*)(ef + (size_t)rc1.y * 16);
        const float4* e2 = (const float4*)(ef + (size_t)rc2.y * 16);
        const float4* e3 = (const float4*)(ef + (size_t)rc3.y * 16);
        float4 a0 = e0[0], b0 = e0[1], c0 = e0[2], d0v = e0[3];
        float4 a1 = e1[0], b1 = e1[1], c1 = e1[2], d1v = e1[3];
        float4 a2 = e2[0], b2 = e2[1], c2 = e2[2], d2v = e2[3];
        float4 a3 = e3[0], b3 = e3[1], c3 = e3[2], d3v = e3[3];
        BODY(pw0, a0, b0, c0, d0v, rc0.z);
        if (p + 1 < off1) BODY(pw1, a1, b1, c1, d1v, rc1.z);
        if (p + 2 < off1) BODY(pw2, a2, b2, c2, d2v, rc2.z);
        if (p + 3 < off1) BODY(pw3, a3, b3, c3, d3v, rc3.z);
    }
#undef BODY

    size_t xb = (size_t)n * 896 + 128;
    float2 hv = *(const float2*)&h[(size_t)n * 128 + d0];
    float o[12];
    if (deg > 0) {
        float inv = 1.f / (float)deg;
        float mean0 = s0 * inv, mean1 = s1 * inv;
        float var0 = fmaxf(ss0 * inv - mean0 * mean0, 0.f);
        float var1 = fmaxf(ss1 * inv - mean1 * mean1, 0.f);
        float sd0 = sqrtf(var0 + 1e-5f), sd1 = sqrtf(var1 + 1e-5f);
        float idn = 1.f / (den + 1e-8f);
        o[0] = mean0; o[1] = mean1; o[2] = mx0; o[3] = mx1; o[4] = mn0; o[5] = mn1;
        o[6] = sd0; o[7] = sd1; o[8] = av0 * idn; o[9] = av1 * idn;
        o[10] = dv0 * idn - hv.x; o[11] = dv1 * idn - hv.y;
    } else {
#pragma unroll
        for (int k = 0; k < 12; ++k) o[k] = 0.f;
    }
#pragma unroll
    for (int a = 0; a < 6; ++a) {
        uint_t w = (uint_t)f2b(o[2 * a]) | ((uint_t)f2b(o[2 * a + 1]) << 16);
        *(uint_t*)&X[xb + a * 128 + d0] = w;
    }
    if (lane == 0) {
        float degc = deg > 0 ? (float)deg : 1.f;
        float logd = logf(degc + 1.f);
        scal[n * 2] = logd * (1.f / 2.772588722239781f);
        scal[n * 2 + 1] = 2.772588722239781f / logd;
    }
}

// ---------------------------------------------------------------- epilogue
__global__ __launch_bounds__(256) void epilogue_kernel(
    const float* __restrict__ O3, const float* __restrict__ h,
    const float* __restrict__ snorm, const float* __restrict__ scal,
    const float* __restrict__ b_post, float* __restrict__ out, int Nn) {
    int g = blockIdx.x * 256 + threadIdx.x;
    if (g >= Nn * 32) return;
    int n = g >> 5, c4 = (g & 31) * 4;
    float a = scal[n * 2], b = scal[n * 2 + 1], sn = snorm[n];
    const float* base = O3 + (size_t)n * 384 + c4;
    float4 o1 = *(const float4*)base;
    float4 o2 = *(const float4*)(base + 128);
    float4 o3 = *(const float4*)(base + 256);
    float4 bp = *(const float4*)&b_post[c4];
    float4 hv = *(const float4*)&h[(size_t)n * 128 + c4];
    float4 r;
    r.x = fmaxf((o1.x + a * o2.x + b * o3.x + bp.x) * sn, 0.f) + hv.x;
    r.y = fmaxf((o1.y + a * o2.y + b * o3.y + bp.y) * sn, 0.f) + hv.y;
    r.z = fmaxf((o1.z + a * o2.z + b * o3.z + bp.z) * sn, 0.f) + hv.z;
    r.w = fmaxf((o1.w + a * o2.w + b * o3.w + bp.w) * sn, 0.f) + hv.w;
    *(float4*)&out[(size_t)n * 128 + c4] = r;
}

// ---------------------------------------------------------------- launch
extern "C" void kernel_launch(void* const* d_in, const int* in_sizes, int n_in,
                              void* d_out, int out_size, void* d_ws, size_t ws_size,
                              hipStream_t stream) {
    const float* h      = (const float*)d_in[0];
    const float* ef     = (const float*)d_in[1];
    const float* eig    = (const float*)d_in[2];
    const float* snorm  = (const float*)d_in[3];
    const int*   src    = (const int*)d_in[4];
    const int*   dst    = (const int*)d_in[5];
    const float* W_pre  = (const float*)d_in[6];
    const float* b_pre  = (const float*)d_in[7];
    const float* W_post = (const float*)d_in[8];
    const float* b_post = (const float*)d_in[9];
    int Nn = in_sizes[0] / 128;
    int E  = in_sizes[4];
    float* out = (float*)d_out;

    char* ws = (char*)d_ws;
    size_t off = 0;
    auto alloc = [&](size_t bytes) {
        size_t o = off;
        off = (off + bytes + 255) & ~(size_t)255;
        return o;
    };
    size_t o_counts  = alloc(((size_t)Nn + 1) * 4);
    size_t o_cursors = alloc((size_t)Nn * 4);
    size_t o_esl     = alloc((size_t)E * 16);
    size_t o_PQ      = alloc((size_t)Nn * 256 * 2);
    size_t o_X       = alloc((size_t)Nn * 896 * 2);
    size_t o_O3      = alloc((size_t)Nn * 384 * 4);
    size_t o_scal    = alloc((size_t)Nn * 2 * 4);
    size_t o_wb      = alloc(256 * 128 * 2);
    size_t o_wc      = alloc(384 * 896 * 2);
    (void)ws_size;

    int*      counts  = (int*)(ws + o_counts);
    int*      cursors = (int*)(ws + o_cursors);
    int4*     esl     = (int4*)(ws + o_esl);
    ushort_t* PQ      = (ushort_t*)(ws + o_PQ);
    ushort_t* X       = (ushort_t*)(ws + o_X);
    float*    O3      = (float*)(ws + o_O3);
    float*    scal    = (float*)(ws + o_scal);
    ushort_t* WbT     = (ushort_t*)(ws + o_wb);
    ushort_t* WcT     = (ushort_t*)(ws + o_wc);

    zero_kernel<<<(Nn + 1 + 255) / 256, 256, 0, stream>>>(counts, Nn + 1);
    pack_wb<<<(256 * 128 + 255) / 256, 256, 0, stream>>>(W_pre, WbT);
    pack_wc<<<(384 * 896 + 255) / 256, 256, 0, stream>>>(W_post, WcT);
    conv_h<<<(Nn * 32 + 255) / 256, 256, 0, stream>>>(h, X, Nn);
    hist_kernel<<<(E + 255) / 256, 256, 0, stream>>>(dst, counts, E);
    scan_kernel<<<1, 1024, 0, stream>>>(counts, cursors, Nn);
    scatter_kernel<<<(E + 255) / 256, 256, 0, stream>>>(dst, src, eig, cursors, esl, E);

    int mt = (Nn + 127) / 128;
    gemm_bt<1><<<mt * 2, 256, 0, stream>>>(X, 896, WbT, 128, (void*)PQ, 256, Nn, 128, 2);

    agg_fused<<<(Nn + 3) / 4, 256, 0, stream>>>(PQ, X, esl, counts, eig, h, ef,
                                                W_pre, b_pre, scal, Nn);

    gemm_bt<0><<<mt * 3, 256, 0, stream>>>(X, 896, WcT, 896, (void*)O3, 384, Nn, 896, 3);

    epilogue_kernel<<<(Nn * 32 + 255) / 256, 256, 0, stream>>>(O3, h, snorm, scal, b_post,
                                                               out, Nn);
}